// Round 2
// baseline (10898.884 us; speedup 1.0000x reference)
//
#include <hip/hip_runtime.h>

#define N_FEAT 256
#define N_FILT 256

// ---------------------------------------------------------------------------
// GEMM: XF[m][n] = sum_k x[m][k] * F[k][n]     (M x 256 x 256, f32)
// Block: 256 threads. Tile: BM=64 rows x BN=128 cols. Thread: 8 rows x 4 cols.
// x tile staged in LDS (64KB); F rows streamed from global (L2-hot, 256KB).
// LDS reads are wave-broadcast (all lanes in a half-wave read the same row) ->
// conflict-free.
// ---------------------------------------------------------------------------
__global__ __launch_bounds__(256) void gemm_xf(const float* __restrict__ x,
                                               const float* __restrict__ F,
                                               float* __restrict__ XF, int M) {
  __shared__ float xs[64][N_FEAT];  // 64 KB
  const int t = threadIdx.x;
  const int row0 = blockIdx.x * 64;
  const int rows = min(64, M - row0);

  // Stage x tile: 64*256 floats = 4096 float4; 16 float4 per thread, coalesced.
  const float4* xv = (const float4*)(x + (size_t)row0 * N_FEAT);
  float4* xsv = (float4*)&xs[0][0];
#pragma unroll
  for (int j = 0; j < 16; ++j) {
    int i = j * 256 + t;           // float4 index; 64 float4 per row
    int r = i >> 6;
    float4 v;
    if (r < rows) v = xv[i];
    else          v = make_float4(0.f, 0.f, 0.f, 0.f);
    xsv[i] = v;
  }
  __syncthreads();

  const int r0 = (t >> 5) * 8;                    // 8 row-groups
  const int c0 = blockIdx.y * 128 + (t & 31) * 4; // 32 col-groups * 4

  float acc[8][4];
#pragma unroll
  for (int r = 0; r < 8; ++r)
#pragma unroll
    for (int c = 0; c < 4; ++c) acc[r][c] = 0.f;

  for (int k = 0; k < N_FEAT; k += 4) {
    float4 f0 = *(const float4*)(F + (size_t)(k + 0) * N_FILT + c0);
    float4 f1 = *(const float4*)(F + (size_t)(k + 1) * N_FILT + c0);
    float4 f2 = *(const float4*)(F + (size_t)(k + 2) * N_FILT + c0);
    float4 f3 = *(const float4*)(F + (size_t)(k + 3) * N_FILT + c0);
#pragma unroll
    for (int r = 0; r < 8; ++r) {
      float4 xr = *(const float4*)&xs[r0 + r][k];
      acc[r][0] += xr.x * f0.x + xr.y * f1.x + xr.z * f2.x + xr.w * f3.x;
      acc[r][1] += xr.x * f0.y + xr.y * f1.y + xr.z * f2.y + xr.w * f3.y;
      acc[r][2] += xr.x * f0.z + xr.y * f1.z + xr.z * f2.z + xr.w * f3.z;
      acc[r][3] += xr.x * f0.w + xr.y * f1.w + xr.z * f2.w + xr.w * f3.w;
    }
  }

#pragma unroll
  for (int r = 0; r < 8; ++r) {
    int row = r0 + r;
    if (row < rows) {
      float4 v = make_float4(acc[r][0], acc[r][1], acc[r][2], acc[r][3]);
      *(float4*)(XF + (size_t)(row0 + row) * N_FILT + c0) = v;
    }
  }
}

// ---------------------------------------------------------------------------
// Scatter: out[row[e]] += w[e] * XF[col[e]]   (atomic f32)
// One wave (64 lanes) per edge; lane l moves features [4l, 4l+4) as float4.
// Reads of XF rows are fully coalesced (1KB contiguous per edge).
// ---------------------------------------------------------------------------
__global__ __launch_bounds__(256) void scatter_edges(
    const float* __restrict__ XF, const int* __restrict__ erow,
    const int* __restrict__ ecol, const float* __restrict__ ew,
    float* __restrict__ out, int nE) {
  const int lane = threadIdx.x & 63;
  const int wid = (blockIdx.x * blockDim.x + threadIdx.x) >> 6;
  const int nwaves = (gridDim.x * blockDim.x) >> 6;

  for (int e = wid; e < nE; e += nwaves) {
    const int r = erow[e];
    const int c = ecol[e];
    const float w = ew[e];
    float4 v = *(const float4*)(XF + (size_t)c * N_FILT + lane * 4);
    float* dst = out + (size_t)r * N_FILT + lane * 4;
    atomicAdd(dst + 0, w * v.x);
    atomicAdd(dst + 1, w * v.y);
    atomicAdd(dst + 2, w * v.z);
    atomicAdd(dst + 3, w * v.w);
  }
}

extern "C" void kernel_launch(void* const* d_in, const int* in_sizes, int n_in,
                              void* d_out, int out_size, void* d_ws, size_t ws_size,
                              hipStream_t stream) {
  const float* x   = (const float*)d_in[0];
  const float* F   = (const float*)d_in[1];
  const int* erow  = (const int*)d_in[2];
  const int* ecol  = (const int*)d_in[3];
  const float* ew  = (const float*)d_in[4];
  float* out       = (float*)d_out;

  const int M  = in_sizes[0] / N_FEAT;
  const int nE = in_sizes[2];

  float* XF = (float*)d_ws;  // M * 256 f32 = 102.4 MB scratch

  hipMemsetAsync(d_out, 0, (size_t)out_size * sizeof(float), stream);

  dim3 gg((M + 63) / 64, N_FILT / 128);
  gemm_xf<<<gg, 256, 0, stream>>>(x, F, XF, M);

  scatter_edges<<<2048, 256, 0, stream>>>(XF, erow, ecol, ew, out, nE);
}

// Round 3
// 989.482 us; speedup vs baseline: 11.0147x; 11.0147x over previous
//
#include <hip/hip_runtime.h>

#define NF 256   // input features
#define NK 256   // filters / output features

// ---------------------------------------------------------------------------
// GEMM: XF[m][n] = sum_k x[m][k] * F[k][n]     (M x 256 x 256, f32)
// ---------------------------------------------------------------------------
__global__ __launch_bounds__(256) void gemm_xf(const float* __restrict__ x,
                                               const float* __restrict__ F,
                                               float* __restrict__ XF, int M) {
  __shared__ float xs[64][NF];  // 64 KB
  const int t = threadIdx.x;
  const int row0 = blockIdx.x * 64;
  const int rows = min(64, M - row0);

  const float4* xv = (const float4*)(x + (size_t)row0 * NF);
  float4* xsv = (float4*)&xs[0][0];
#pragma unroll
  for (int j = 0; j < 16; ++j) {
    int i = j * 256 + t;
    int r = i >> 6;
    float4 v;
    if (r < rows) v = xv[i];
    else          v = make_float4(0.f, 0.f, 0.f, 0.f);
    xsv[i] = v;
  }
  __syncthreads();

  const int r0 = (t >> 5) * 8;
  const int c0 = blockIdx.y * 128 + (t & 31) * 4;

  float acc[8][4];
#pragma unroll
  for (int r = 0; r < 8; ++r)
#pragma unroll
    for (int c = 0; c < 4; ++c) acc[r][c] = 0.f;

  for (int k = 0; k < NF; k += 4) {
    float4 f0 = *(const float4*)(F + (size_t)(k + 0) * NK + c0);
    float4 f1 = *(const float4*)(F + (size_t)(k + 1) * NK + c0);
    float4 f2 = *(const float4*)(F + (size_t)(k + 2) * NK + c0);
    float4 f3 = *(const float4*)(F + (size_t)(k + 3) * NK + c0);
#pragma unroll
    for (int r = 0; r < 8; ++r) {
      float4 xr = *(const float4*)&xs[r0 + r][k];
      acc[r][0] += xr.x * f0.x + xr.y * f1.x + xr.z * f2.x + xr.w * f3.x;
      acc[r][1] += xr.x * f0.y + xr.y * f1.y + xr.z * f2.y + xr.w * f3.y;
      acc[r][2] += xr.x * f0.z + xr.y * f1.z + xr.z * f2.z + xr.w * f3.z;
      acc[r][3] += xr.x * f0.w + xr.y * f1.w + xr.z * f2.w + xr.w * f3.w;
    }
  }

#pragma unroll
  for (int r = 0; r < 8; ++r) {
    int row = r0 + r;
    if (row < rows) {
      float4 v = make_float4(acc[r][0], acc[r][1], acc[r][2], acc[r][3]);
      *(float4*)(XF + (size_t)(row0 + row) * NK + c0) = v;
    }
  }
}

// ---------------------------------------------------------------------------
// CSR build: histogram -> 3-kernel exclusive scan -> bucket scatter
// ---------------------------------------------------------------------------
__global__ __launch_bounds__(256) void hist_rows(const int* __restrict__ erow,
                                                 int* __restrict__ cnt, int nE) {
  for (int e = blockIdx.x * blockDim.x + threadIdx.x; e < nE;
       e += gridDim.x * blockDim.x)
    atomicAdd(&cnt[erow[e]], 1);
}

__global__ __launch_bounds__(256) void block_reduce(const int* __restrict__ cnt,
                                                    int* __restrict__ bsums, int n) {
  __shared__ int s[256];
  int i = blockIdx.x * 256 + threadIdx.x;
  s[threadIdx.x] = (i < n) ? cnt[i] : 0;
  __syncthreads();
  for (int d = 128; d > 0; d >>= 1) {
    if (threadIdx.x < d) s[threadIdx.x] += s[threadIdx.x + d];
    __syncthreads();
  }
  if (threadIdx.x == 0) bsums[blockIdx.x] = s[0];
}

__global__ __launch_bounds__(512) void scan_bsums(int* bsums, int nb) {
  __shared__ int s[512];
  int t = threadIdx.x;
  int v = (t < nb) ? bsums[t] : 0;
  s[t] = v;
  __syncthreads();
  for (int d = 1; d < 512; d <<= 1) {
    int tmp = (t >= d) ? s[t - d] : 0;
    __syncthreads();
    s[t] += tmp;
    __syncthreads();
  }
  if (t < nb) bsums[t] = s[t] - v;  // exclusive
}

__global__ __launch_bounds__(256) void scan_blocks(const int* __restrict__ cnt,
                                                   const int* __restrict__ bsums,
                                                   int* __restrict__ offsets,
                                                   int* __restrict__ cursor, int n) {
  __shared__ int s[256];
  int t = threadIdx.x;
  int i = blockIdx.x * 256 + t;
  int v = (i < n) ? cnt[i] : 0;
  s[t] = v;
  __syncthreads();
  for (int d = 1; d < 256; d <<= 1) {
    int tmp = (t >= d) ? s[t - d] : 0;
    __syncthreads();
    s[t] += tmp;
    __syncthreads();
  }
  int excl = s[t] - v + bsums[blockIdx.x];
  if (i < n) { offsets[i] = excl; cursor[i] = excl; }
  if (i == n - 1) offsets[n] = excl + v;
}

__global__ __launch_bounds__(256) void bucket_edges(const int* __restrict__ erow,
                                                    const int* __restrict__ ecol,
                                                    const float* __restrict__ ew,
                                                    int* __restrict__ cursor,
                                                    int2* __restrict__ cw, int nE) {
  for (int e = blockIdx.x * blockDim.x + threadIdx.x; e < nE;
       e += gridDim.x * blockDim.x) {
    int d = atomicAdd(&cursor[erow[e]], 1);
    cw[d] = make_int2(ecol[e], __float_as_int(ew[e]));
  }
}

// ---------------------------------------------------------------------------
// Gather: one wave per node. Lanes preload up to 64 (col,w) pairs; each edge
// is broadcast via __shfl, lane l accumulates features [4l,4l+4) as float4.
// XF row reads are coalesced 1KB; out written exactly once, no atomics.
// ---------------------------------------------------------------------------
__global__ __launch_bounds__(256) void gather_csr(const float4* __restrict__ XFv,
                                                  const int* __restrict__ offsets,
                                                  const int2* __restrict__ cw,
                                                  float4* __restrict__ outv,
                                                  int nNodes) {
  const int lane = threadIdx.x & 63;
  const int node = (blockIdx.x * blockDim.x + threadIdx.x) >> 6;
  if (node >= nNodes) return;
  const int start = offsets[node];
  const int end   = offsets[node + 1];

  float4 acc = make_float4(0.f, 0.f, 0.f, 0.f);
  for (int base = start; base < end; base += 64) {
    int n = end - base;
    if (n > 64) n = 64;
    int2 e = make_int2(0, 0);
    if (lane < n) e = cw[base + lane];
    int j = 0;
    for (; j + 1 < n; j += 2) {
      int   c0 = __shfl(e.x, j);
      int   c1 = __shfl(e.x, j + 1);
      float w0 = __int_as_float(__shfl(e.y, j));
      float w1 = __int_as_float(__shfl(e.y, j + 1));
      float4 v0 = XFv[(size_t)c0 * 64 + lane];
      float4 v1 = XFv[(size_t)c1 * 64 + lane];
      acc.x += w0 * v0.x; acc.y += w0 * v0.y; acc.z += w0 * v0.z; acc.w += w0 * v0.w;
      acc.x += w1 * v1.x; acc.y += w1 * v1.y; acc.z += w1 * v1.z; acc.w += w1 * v1.w;
    }
    if (j < n) {
      int   c0 = __shfl(e.x, j);
      float w0 = __int_as_float(__shfl(e.y, j));
      float4 v0 = XFv[(size_t)c0 * 64 + lane];
      acc.x += w0 * v0.x; acc.y += w0 * v0.y; acc.z += w0 * v0.z; acc.w += w0 * v0.w;
    }
  }
  outv[(size_t)node * 64 + lane] = acc;
}

// ---------------------------------------------------------------------------
// Fallback atomic scatter (used only if ws_size is too small for CSR build)
// ---------------------------------------------------------------------------
__global__ __launch_bounds__(256) void scatter_edges(
    const float* __restrict__ XF, const int* __restrict__ erow,
    const int* __restrict__ ecol, const float* __restrict__ ew,
    float* __restrict__ out, int nE) {
  const int lane = threadIdx.x & 63;
  const int wid = (blockIdx.x * blockDim.x + threadIdx.x) >> 6;
  const int nwaves = (gridDim.x * blockDim.x) >> 6;
  for (int e = wid; e < nE; e += nwaves) {
    const int r = erow[e];
    const int c = ecol[e];
    const float w = ew[e];
    float4 v = *(const float4*)(XF + (size_t)c * NK + lane * 4);
    float* dst = out + (size_t)r * NK + lane * 4;
    atomicAdd(dst + 0, w * v.x);
    atomicAdd(dst + 1, w * v.y);
    atomicAdd(dst + 2, w * v.z);
    atomicAdd(dst + 3, w * v.w);
  }
}

static inline size_t align16(size_t x) { return (x + 15) & ~(size_t)15; }

extern "C" void kernel_launch(void* const* d_in, const int* in_sizes, int n_in,
                              void* d_out, int out_size, void* d_ws, size_t ws_size,
                              hipStream_t stream) {
  const float* x   = (const float*)d_in[0];
  const float* F   = (const float*)d_in[1];
  const int* erow  = (const int*)d_in[2];
  const int* ecol  = (const int*)d_in[3];
  const float* ew  = (const float*)d_in[4];
  float* out       = (float*)d_out;

  const int M      = in_sizes[0] / NF;   // rows of x (gather source)
  const int nE     = in_sizes[2];
  const int nNodes = out_size / NK;      // output rows (scatter dest)

  // ---- workspace layout ----
  char* base = (char*)d_ws;
  size_t off = 0;
  float* XF = (float*)(base + off);  off += align16((size_t)M * NK * sizeof(float));
  int* cnt     = (int*)(base + off); off += align16((size_t)nNodes * sizeof(int));
  int* offsets = (int*)(base + off); off += align16(((size_t)nNodes + 1) * sizeof(int));
  int* cursor  = (int*)(base + off); off += align16((size_t)nNodes * sizeof(int));
  int* bsums   = (int*)(base + off); off += align16(512 * sizeof(int));
  int2* cw     = (int2*)(base + off); off += align16((size_t)nE * sizeof(int2));
  const size_t needed = off;
  const int nb = (nNodes + 255) / 256;

  // ---- GEMM ----
  dim3 gg((M + 63) / 64, NK / 128);
  gemm_xf<<<gg, 256, 0, stream>>>(x, F, XF, M);

  if (ws_size >= needed && nb <= 512) {
    // ---- CSR build ----
    hipMemsetAsync(cnt, 0, (size_t)nNodes * sizeof(int), stream);
    hist_rows<<<2048, 256, 0, stream>>>(erow, cnt, nE);
    block_reduce<<<nb, 256, 0, stream>>>(cnt, bsums, nNodes);
    scan_bsums<<<1, 512, 0, stream>>>(bsums, nb);
    scan_blocks<<<nb, 256, 0, stream>>>(cnt, bsums, offsets, cursor, nNodes);
    bucket_edges<<<2048, 256, 0, stream>>>(erow, ecol, ew, cursor, cw, nE);
    // ---- gather (writes every output row exactly once; no memset needed) ----
    int gblocks = (nNodes + 3) / 4;  // 4 waves (nodes) per 256-thread block
    gather_csr<<<gblocks, 256, 0, stream>>>((const float4*)XF, offsets, cw,
                                            (float4*)out, nNodes);
  } else {
    // ---- fallback: atomic scatter ----
    hipMemsetAsync(d_out, 0, (size_t)out_size * sizeof(float), stream);
    scatter_edges<<<2048, 256, 0, stream>>>(XF, erow, ecol, ew, out, nE);
  }
}

// Round 4
// 678.608 us; speedup vs baseline: 16.0606x; 1.4581x over previous
//
#include <hip/hip_runtime.h>

#define NF 256   // input features
#define NK 256   // filters / output features

typedef __attribute__((ext_vector_type(8))) short bf16x8;
typedef __attribute__((ext_vector_type(4))) float f32x4;

__device__ __forceinline__ ushort f2bf(float f) {
  uint u = __float_as_uint(f);
  return (ushort)((u + 0x7fffu + ((u >> 16) & 1u)) >> 16);  // RNE
}
__device__ __forceinline__ float bf2f(ushort h) {
  return __uint_as_float(((uint)h) << 16);
}

// ---------------------------------------------------------------------------
// Filters f32 [K][N] -> bf16 transposed Ft [N][K]  (tiny: 128KB out)
// ---------------------------------------------------------------------------
__global__ __launch_bounds__(256) void cvt_filters(const float* __restrict__ F,
                                                   ushort* __restrict__ Ft) {
  int k = blockIdx.x;   // 0..255
  int n = threadIdx.x;  // 0..255
  Ft[(size_t)n * NF + k] = f2bf(F[(size_t)k * NK + n]);
}

// ---------------------------------------------------------------------------
// MFMA GEMM: XFh[m][n] = sum_k x[m][k]*F[k][n], bf16 in/out, f32 accum.
// Block = 256 thr (4 waves). Block tile: 16 rows x 256 cols; wave: 16x64.
// A tile (16x256 bf16) staged in LDS with XOR swizzle; x converted on the fly.
// B frags read from Ft (bf16 [N][K], contiguous-K) — 128KB, L1/L2-hot.
// Frag layout (guide §3): A row=lane&15, k=(lane>>4)*8+e (contig 8);
// B col=lane&15, same k; D col=lane&15, row=(lane>>4)*4+reg.
// ---------------------------------------------------------------------------
__global__ __launch_bounds__(256) void gemm_mfma(const float* __restrict__ x,
                                                 const ushort* __restrict__ Ft,
                                                 ushort* __restrict__ XFh, int M) {
  __shared__ ushort As[16 * NF];  // 8 KB, swizzled
  const int t = threadIdx.x;
  const int row0 = blockIdx.x * 16;

  // stage 16 rows x 256 k of x, f32 -> bf16: 1024 float4 reads, 4 per thread
  const float4* xv = (const float4*)(x + (size_t)row0 * NF);
#pragma unroll
  for (int j = 0; j < 4; ++j) {
    int idx = j * 256 + t;   // 0..1023
    int r = idx >> 6;        // row 0..15
    int c4 = idx & 63;       // float4 index within row
    float4 v = make_float4(0.f, 0.f, 0.f, 0.f);
    if (row0 + r < M) v = xv[idx];
    ushort4 h = make_ushort4(f2bf(v.x), f2bf(v.y), f2bf(v.z), f2bf(v.w));
    uint boff = (uint)(r * 512 + c4 * 8);
    boff ^= (uint)((r & 7) << 4);
    *(ushort4*)((char*)As + boff) = h;
  }
  __syncthreads();

  const int lane = t & 63;
  const int wv = t >> 6;
  const int arow = lane & 15;
  const int kg = lane >> 4;

  bf16x8 afr[8];
#pragma unroll
  for (int kk = 0; kk < 8; ++kk) {
    uint boff = (uint)(arow * 512 + kk * 64 + kg * 16);
    boff ^= (uint)((arow & 7) << 4);
    afr[kk] = *(const bf16x8*)((const char*)As + boff);
  }

  f32x4 acc[4];
#pragma unroll
  for (int f = 0; f < 4; ++f) acc[f] = (f32x4){0.f, 0.f, 0.f, 0.f};

  const int ncol0 = wv * 64;
#pragma unroll
  for (int f = 0; f < 4; ++f) {
    const ushort* bp = Ft + (size_t)(ncol0 + f * 16 + arow) * NF + kg * 8;
#pragma unroll
    for (int kk = 0; kk < 8; ++kk) {
      bf16x8 bfr = *(const bf16x8*)(bp + kk * 32);
      acc[f] = __builtin_amdgcn_mfma_f32_16x16x32_bf16(afr[kk], bfr, acc[f], 0, 0, 0);
    }
  }

#pragma unroll
  for (int f = 0; f < 4; ++f) {
    int col = ncol0 + f * 16 + arow;
#pragma unroll
    for (int rg = 0; rg < 4; ++rg) {
      int row = row0 + kg * 4 + rg;
      if (row < M) XFh[(size_t)row * NK + col] = f2bf(acc[f][rg]);
    }
  }
}

// ---------------------------------------------------------------------------
// CSR build: histogram -> 3-kernel exclusive scan -> bucket scatter
// ---------------------------------------------------------------------------
__global__ __launch_bounds__(256) void hist_rows(const int* __restrict__ erow,
                                                 int* __restrict__ cnt, int nE) {
  for (int e = blockIdx.x * blockDim.x + threadIdx.x; e < nE;
       e += gridDim.x * blockDim.x)
    atomicAdd(&cnt[erow[e]], 1);
}

__global__ __launch_bounds__(256) void block_reduce(const int* __restrict__ cnt,
                                                    int* __restrict__ bsums, int n) {
  __shared__ int s[256];
  int i = blockIdx.x * 256 + threadIdx.x;
  s[threadIdx.x] = (i < n) ? cnt[i] : 0;
  __syncthreads();
  for (int d = 128; d > 0; d >>= 1) {
    if (threadIdx.x < d) s[threadIdx.x] += s[threadIdx.x + d];
    __syncthreads();
  }
  if (threadIdx.x == 0) bsums[blockIdx.x] = s[0];
}

__global__ __launch_bounds__(512) void scan_bsums(int* bsums, int nb) {
  __shared__ int s[512];
  int t = threadIdx.x;
  int v = (t < nb) ? bsums[t] : 0;
  s[t] = v;
  __syncthreads();
  for (int d = 1; d < 512; d <<= 1) {
    int tmp = (t >= d) ? s[t - d] : 0;
    __syncthreads();
    s[t] += tmp;
    __syncthreads();
  }
  if (t < nb) bsums[t] = s[t] - v;  // exclusive
}

__global__ __launch_bounds__(256) void scan_blocks(const int* __restrict__ cnt,
                                                   const int* __restrict__ bsums,
                                                   int* __restrict__ offsets,
                                                   int* __restrict__ cursor, int n) {
  __shared__ int s[256];
  int t = threadIdx.x;
  int i = blockIdx.x * 256 + t;
  int v = (i < n) ? cnt[i] : 0;
  s[t] = v;
  __syncthreads();
  for (int d = 1; d < 256; d <<= 1) {
    int tmp = (t >= d) ? s[t - d] : 0;
    __syncthreads();
    s[t] += tmp;
    __syncthreads();
  }
  int excl = s[t] - v + bsums[blockIdx.x];
  if (i < n) { offsets[i] = excl; cursor[i] = excl; }
  if (i == n - 1) offsets[n] = excl + v;
}

__global__ __launch_bounds__(256) void bucket_edges(const int* __restrict__ erow,
                                                    const int* __restrict__ ecol,
                                                    const float* __restrict__ ew,
                                                    int* __restrict__ cursor,
                                                    int2* __restrict__ cw, int nE) {
  for (int e = blockIdx.x * blockDim.x + threadIdx.x; e < nE;
       e += gridDim.x * blockDim.x) {
    int d = atomicAdd(&cursor[erow[e]], 1);
    cw[d] = make_int2(ecol[e], __float_as_int(ew[e]));
  }
}

// ---------------------------------------------------------------------------
// Gather (bf16 XF): one wave per node; lanes preload <=64 (col,w) pairs,
// broadcast via shfl; lane l holds features [4l,4l+4). 4-edge unroll for MLP.
// Each XF row read = 512B coalesced (64 lanes x 8B ushort4).
// ---------------------------------------------------------------------------
__global__ __launch_bounds__(256) void gather_bf16(const ushort* __restrict__ XFh,
                                                   const int* __restrict__ offsets,
                                                   const int2* __restrict__ cw,
                                                   float4* __restrict__ outv,
                                                   int nNodes) {
  const int lane = threadIdx.x & 63;
  const int node = (blockIdx.x * blockDim.x + threadIdx.x) >> 6;
  if (node >= nNodes) return;
  const int start = offsets[node];
  const int end = offsets[node + 1];
  const ushort4* XV = (const ushort4*)XFh;  // 64 ushort4 per row

  float ax = 0.f, ay = 0.f, az = 0.f, aw = 0.f;
  for (int base = start; base < end; base += 64) {
    int n = end - base;
    if (n > 64) n = 64;
    int2 e = make_int2(0, 0);
    if (lane < n) e = cw[base + lane];
    int j = 0;
    for (; j + 3 < n; j += 4) {
      int c0 = __shfl(e.x, j),     c1 = __shfl(e.x, j + 1);
      int c2 = __shfl(e.x, j + 2), c3 = __shfl(e.x, j + 3);
      float w0 = __int_as_float(__shfl(e.y, j));
      float w1 = __int_as_float(__shfl(e.y, j + 1));
      float w2 = __int_as_float(__shfl(e.y, j + 2));
      float w3 = __int_as_float(__shfl(e.y, j + 3));
      ushort4 v0 = XV[(size_t)c0 * 64 + lane];
      ushort4 v1 = XV[(size_t)c1 * 64 + lane];
      ushort4 v2 = XV[(size_t)c2 * 64 + lane];
      ushort4 v3 = XV[(size_t)c3 * 64 + lane];
      ax += w0 * bf2f(v0.x); ay += w0 * bf2f(v0.y); az += w0 * bf2f(v0.z); aw += w0 * bf2f(v0.w);
      ax += w1 * bf2f(v1.x); ay += w1 * bf2f(v1.y); az += w1 * bf2f(v1.z); aw += w1 * bf2f(v1.w);
      ax += w2 * bf2f(v2.x); ay += w2 * bf2f(v2.y); az += w2 * bf2f(v2.z); aw += w2 * bf2f(v2.w);
      ax += w3 * bf2f(v3.x); ay += w3 * bf2f(v3.y); az += w3 * bf2f(v3.z); aw += w3 * bf2f(v3.w);
    }
    for (; j < n; ++j) {
      int c0 = __shfl(e.x, j);
      float w0 = __int_as_float(__shfl(e.y, j));
      ushort4 v0 = XV[(size_t)c0 * 64 + lane];
      ax += w0 * bf2f(v0.x); ay += w0 * bf2f(v0.y); az += w0 * bf2f(v0.z); aw += w0 * bf2f(v0.w);
    }
  }
  outv[(size_t)node * 64 + lane] = make_float4(ax, ay, az, aw);
}

// ---------------------------------------------------------------------------
// Fallback path (ws too small): f32 GEMM + atomic scatter
// ---------------------------------------------------------------------------
__global__ __launch_bounds__(256) void gemm_xf(const float* __restrict__ x,
                                               const float* __restrict__ F,
                                               float* __restrict__ XF, int M) {
  __shared__ float xs[64][NF];
  const int t = threadIdx.x;
  const int row0 = blockIdx.x * 64;
  const int rows = min(64, M - row0);
  const float4* xv = (const float4*)(x + (size_t)row0 * NF);
  float4* xsv = (float4*)&xs[0][0];
#pragma unroll
  for (int j = 0; j < 16; ++j) {
    int i = j * 256 + t;
    int r = i >> 6;
    float4 v;
    if (r < rows) v = xv[i];
    else          v = make_float4(0.f, 0.f, 0.f, 0.f);
    xsv[i] = v;
  }
  __syncthreads();
  const int r0 = (t >> 5) * 8;
  const int c0 = blockIdx.y * 128 + (t & 31) * 4;
  float acc[8][4];
#pragma unroll
  for (int r = 0; r < 8; ++r)
#pragma unroll
    for (int c = 0; c < 4; ++c) acc[r][c] = 0.f;
  for (int k = 0; k < NF; k += 4) {
    float4 f0 = *(const float4*)(F + (size_t)(k + 0) * NK + c0);
    float4 f1 = *(const float4*)(F + (size_t)(k + 1) * NK + c0);
    float4 f2 = *(const float4*)(F + (size_t)(k + 2) * NK + c0);
    float4 f3 = *(const float4*)(F + (size_t)(k + 3) * NK + c0);
#pragma unroll
    for (int r = 0; r < 8; ++r) {
      float4 xr = *(const float4*)&xs[r0 + r][k];
      acc[r][0] += xr.x * f0.x + xr.y * f1.x + xr.z * f2.x + xr.w * f3.x;
      acc[r][1] += xr.x * f0.y + xr.y * f1.y + xr.z * f2.y + xr.w * f3.y;
      acc[r][2] += xr.x * f0.z + xr.y * f1.z + xr.z * f2.z + xr.w * f3.z;
      acc[r][3] += xr.x * f0.w + xr.y * f1.w + xr.z * f2.w + xr.w * f3.w;
    }
  }
#pragma unroll
  for (int r = 0; r < 8; ++r) {
    int row = r0 + r;
    if (row < rows) {
      float4 v = make_float4(acc[r][0], acc[r][1], acc[r][2], acc[r][3]);
      *(float4*)(XF + (size_t)(row0 + row) * NK + c0) = v;
    }
  }
}

__global__ __launch_bounds__(256) void scatter_edges(
    const float* __restrict__ XF, const int* __restrict__ erow,
    const int* __restrict__ ecol, const float* __restrict__ ew,
    float* __restrict__ out, int nE) {
  const int lane = threadIdx.x & 63;
  const int wid = (blockIdx.x * blockDim.x + threadIdx.x) >> 6;
  const int nwaves = (gridDim.x * blockDim.x) >> 6;
  for (int e = wid; e < nE; e += nwaves) {
    const int r = erow[e];
    const int c = ecol[e];
    const float w = ew[e];
    float4 v = *(const float4*)(XF + (size_t)c * NK + lane * 4);
    float* dst = out + (size_t)r * NK + lane * 4;
    atomicAdd(dst + 0, w * v.x);
    atomicAdd(dst + 1, w * v.y);
    atomicAdd(dst + 2, w * v.z);
    atomicAdd(dst + 3, w * v.w);
  }
}

static inline size_t align16(size_t x) { return (x + 15) & ~(size_t)15; }

extern "C" void kernel_launch(void* const* d_in, const int* in_sizes, int n_in,
                              void* d_out, int out_size, void* d_ws, size_t ws_size,
                              hipStream_t stream) {
  const float* x  = (const float*)d_in[0];
  const float* F  = (const float*)d_in[1];
  const int* erow = (const int*)d_in[2];
  const int* ecol = (const int*)d_in[3];
  const float* ew = (const float*)d_in[4];
  float* out      = (float*)d_out;

  const int M      = in_sizes[0] / NF;
  const int nE     = in_sizes[2];
  const int nNodes = out_size / NK;

  // ---- workspace layout (bf16 path) ----
  char* base = (char*)d_ws;
  size_t off = 0;
  ushort* XFh  = (ushort*)(base + off); off += align16((size_t)M * NK * sizeof(ushort));
  ushort* Ft   = (ushort*)(base + off); off += align16((size_t)NF * NK * sizeof(ushort));
  int* cnt     = (int*)(base + off);    off += align16((size_t)nNodes * sizeof(int));
  int* offsets = (int*)(base + off);    off += align16(((size_t)nNodes + 1) * sizeof(int));
  int* cursor  = (int*)(base + off);    off += align16((size_t)nNodes * sizeof(int));
  int* bsums   = (int*)(base + off);    off += align16(512 * sizeof(int));
  int2* cw     = (int2*)(base + off);   off += align16((size_t)nE * sizeof(int2));
  const size_t needed = off;
  const int nb = (nNodes + 255) / 256;

  if (ws_size >= needed && nb <= 512) {
    // ---- GEMM (bf16 MFMA) ----
    cvt_filters<<<NF, NK, 0, stream>>>(F, Ft);
    gemm_mfma<<<(M + 15) / 16, 256, 0, stream>>>(x, Ft, XFh, M);
    // ---- CSR build ----
    hipMemsetAsync(cnt, 0, (size_t)nNodes * sizeof(int), stream);
    hist_rows<<<2048, 256, 0, stream>>>(erow, cnt, nE);
    block_reduce<<<nb, 256, 0, stream>>>(cnt, bsums, nNodes);
    scan_bsums<<<1, 512, 0, stream>>>(bsums, nb);
    scan_blocks<<<nb, 256, 0, stream>>>(cnt, bsums, offsets, cursor, nNodes);
    bucket_edges<<<2048, 256, 0, stream>>>(erow, ecol, ew, cursor, cw, nE);
    // ---- gather (each output row written exactly once) ----
    int gblocks = (nNodes + 3) / 4;
    gather_bf16<<<gblocks, 256, 0, stream>>>(XFh, offsets, cw, (float4*)out, nNodes);
  } else {
    // ---- fallback: f32 GEMM + atomic scatter ----
    float* XF = (float*)d_ws;
    dim3 gg((M + 63) / 64, NK / 128);
    gemm_xf<<<gg, 256, 0, stream>>>(x, F, XF, M);
    hipMemsetAsync(d_out, 0, (size_t)out_size * sizeof(float), stream);
    scatter_edges<<<2048, 256, 0, stream>>>(XF, erow, ecol, ew, out, nE);
  }
}